// Round 1
// 186.806 us; speedup vs baseline: 1.0547x; 1.0547x over previous
//
#include <hip/hip_runtime.h>
#include <hip/hip_bf16.h>

typedef __attribute__((ext_vector_type(8))) short short8;
typedef __attribute__((ext_vector_type(4))) float f32x4;
typedef __attribute__((ext_vector_type(2))) unsigned int uint2v;
typedef __attribute__((ext_vector_type(4))) unsigned int uint4v;
typedef unsigned short u16;

#define MFMA_BF16(a, b, c) __builtin_amdgcn_mfma_f32_16x16x32_bf16(a, b, c, 0, 0, 0)

#define T_SEQ 2048
#define DMODEL 1024
#define NHEADS 16
#define DHEAD 64
#define NEG_BIG (-30000.0f)
#define QSCALE 0.1803368801111f  // 0.125 * log2(e): softmax in exp2 domain
#define RESCALE_THR 8.0f         // defer-max threshold (exp2 domain): P <= 2^8

#if __has_builtin(__builtin_amdgcn_exp2f)
#define EXP2(x) __builtin_amdgcn_exp2f(x)
#else
#define EXP2(x) exp2f(x)
#endif

__device__ __forceinline__ unsigned bfr(unsigned u) {
  return (u + 0x7fffu + ((u >> 16) & 1u)) >> 16;
}
__device__ __forceinline__ uint4v ld8bf(const float* __restrict__ p) {
  const uint4v a = *(const uint4v*)p;
  const uint4v b = *(const uint4v*)(p + 4);
  uint4v r;
  r[0] = bfr(a[0]) | (bfr(a[1]) << 16);
  r[1] = bfr(a[2]) | (bfr(a[3]) << 16);
  r[2] = bfr(b[0]) | (bfr(b[1]) << 16);
  r[3] = bfr(b[2]) | (bfr(b[3]) << 16);
  return r;
}
__device__ __forceinline__ u16 f2bf(float f) {
  unsigned u = __float_as_uint(f);
  u += 0x7fffu + ((u >> 16) & 1u);
  return (u16)(u >> 16);
}
// async global->LDS DMA, 16B per lane; lds dest must be uniform-base + lane*16
__device__ __forceinline__ void gld16(const u16* g, u16* l) {
  __builtin_amdgcn_global_load_lds(
      (const __attribute__((address_space(1))) unsigned int*)g,
      (__attribute__((address_space(3))) unsigned int*)l, 16, 0, 0);
}

// ---------------------------------------------------------------- cvt fp32->bf16
__global__ __launch_bounds__(256) void cvt_all(
    const float* __restrict__ x, const float* __restrict__ wq,
    const float* __restrict__ wk, const float* __restrict__ wv,
    const float* __restrict__ wo, u16* __restrict__ xh, u16* __restrict__ wqh,
    u16* __restrict__ wkh, u16* __restrict__ wvh, u16* __restrict__ woh) {
  int bi = blockIdx.x;
  const float* s;
  u16* d;
  size_t base;
  if (bi < 2048) {
    s = x; d = xh; base = (size_t)bi * 2048;
  } else {
    int k = (bi - 2048) >> 9;
    int r = (bi - 2048) & 511;
    s = (k == 0) ? wq : (k == 1) ? wk : (k == 2) ? wv : wo;
    d = (k == 0) ? wqh : (k == 1) ? wkh : (k == 2) ? wvh : woh;
    base = (size_t)r * 2048;
  }
  size_t i = base + (size_t)threadIdx.x * 8;
  *(uint4v*)&d[i] = ld8bf(&s[i]);
}

// ---------------------------------------------------------------- QKV proj (bf16)
// grid (32,8,3): z=0 Q (pre-scaled by 0.125*log2e), z=1 K -> (b,h,t,d);
// z=2 V -> TRANSPOSED (b,h,d,t). Double-buffered global_load_lds staging:
// issue stage(k+1) BEFORE compute(k); single barrier/iter (T3-min pattern;
// compiler's vmcnt(0)-drain before s_barrier is the counted-wait).
__global__ __launch_bounds__(256) void gemm_qkv(
    const u16* __restrict__ X, const u16* __restrict__ Wq,
    const u16* __restrict__ Wk, const u16* __restrict__ Wv,
    u16* __restrict__ Qo, u16* __restrict__ Ko, u16* __restrict__ Vo) {
  __shared__ __attribute__((aligned(16))) u16 As[2][128 * 32];
  __shared__ __attribute__((aligned(16))) u16 Bs[2][128 * 32];
  const int tid = threadIdx.x, lane = tid & 63, w = tid >> 6;
  const int wm = (w >> 1) * 64, wn = (w & 1) * 64;
  const int lrow = lane & 15;
  const int lk = (lane >> 4) << 3;
  const int lq = (lane >> 4) << 2;
  const int mBase = blockIdx.x * 128, nBase = blockIdx.y * 128;
  const u16* Bt = (blockIdx.z == 0) ? Wq : (blockIdx.z == 1) ? Wk : Wv;
  u16* D = (blockIdx.z == 0) ? Qo : (blockIdx.z == 1) ? Ko : Vo;
  const float scale = (blockIdx.z == 0) ? QSCALE : 1.0f;

  f32x4 acc[4][4];
#pragma unroll
  for (int mi = 0; mi < 4; mi++)
#pragma unroll
    for (int ni = 0; ni < 4; ni++) acc[mi][ni] = (f32x4)0.0f;

  auto stage = [&](int buf, int k0) {
#pragma unroll
    for (int i = 0; i < 2; i++) {
      int c = i * 256 + tid;
      int r = c >> 2, kk = (c & 3) << 3;
      gld16(&X[(size_t)(mBase + r) * 1024 + k0 + kk], &As[buf][c * 8]);
      gld16(&Bt[(size_t)(nBase + r) * 1024 + k0 + kk], &Bs[buf][c * 8]);
    }
  };

  stage(0, 0);
  __syncthreads();
  int cur = 0;
  for (int k0 = 0; k0 < 1024; k0 += 32) {
    if (k0 + 32 < 1024) stage(cur ^ 1, k0 + 32);
    short8 af[4], bf[4];
#pragma unroll
    for (int mi = 0; mi < 4; mi++)
      af[mi] = *(const short8*)&As[cur][(wm + mi * 16 + lrow) * 32 + lk];
#pragma unroll
    for (int ni = 0; ni < 4; ni++)
      bf[ni] = *(const short8*)&Bs[cur][(wn + ni * 16 + lrow) * 32 + lk];
#pragma unroll
    for (int mi = 0; mi < 4; mi++)
#pragma unroll
      for (int ni = 0; ni < 4; ni++)
        acc[mi][ni] = MFMA_BF16(af[mi], bf[ni], acc[mi][ni]);
    __syncthreads();  // drains vmcnt (next tile landed) + lgkm
    cur ^= 1;
  }
  const int vz = (blockIdx.z == 2);
#pragma unroll
  for (int mi = 0; mi < 4; mi++)
#pragma unroll
    for (int r = 0; r < 4; r++) {
      int m = mBase + wm + mi * 16 + lq + r;
      int b = m >> 11, t = m & 2047;
#pragma unroll
      for (int ni = 0; ni < 4; ni++) {
        int n = nBase + wn + ni * 16 + lrow;
        int h = n >> 6, dd = n & 63;
        size_t idx = vz ? (((size_t)((b * NHEADS + h) * DHEAD + dd)) * T_SEQ + t)
                        : ((((size_t)(b * NHEADS + h)) * T_SEQ + t) * DHEAD + dd);
        D[idx] = f2bf(acc[mi][ni][r] * scale);
      }
    }
}

// ---------------------------------------------------------------- attention
// Balanced snake over 64-row Q-tiles; block j handles {j, 31-j}. 256 thr = 4
// waves, wave owns 16 q-rows. S^T formulation: mfma(kf,qf) -> col=lane&15=q,
// so softmax stats are per-lane scalars. V pre-transposed (b,h,d,t).
// K/V: stride-64 rows, double-buffered, staged via global_load_lds with
// rule-21 both-sides XOR swizzle (src col slot ^= row&7; read slot ^= lrow&7)
// -> conflict-free ds_read_b128 + linear DMA dest. Prefetch tile kt+1 before
// computing kt; ONE barrier/iter. Q/P keep padded-72 wave-private region.
__global__ __launch_bounds__(256) void attn_snake(
    const u16* __restrict__ Qg, const u16* __restrict__ Kg,
    const u16* __restrict__ Vtg, u16* __restrict__ Ob) {
  __shared__ __attribute__((aligned(16))) u16 smem[20992];  // 41984 B
  u16* Qs = smem;  // 64*72; aliased as Ps (wave-private rows) in kv loop
  u16* Ps = smem;
  // K bufs: smem+4608 + cur*4096 ; V bufs: smem+12800 + cur*4096

  const int tid = threadIdx.x;
  const int w = tid >> 6, lane = tid & 63;
  const int lrow = lane & 15;
  const int quad = lane >> 4;
  const int lk = quad << 3;
  const int rsw = lrow & 7;           // read-side swizzle key
  const int q_local = w * 16 + lrow;  // this lane's q-row within the 64-tile

  const int j = blockIdx.x;  // 0..15
  const int bh = blockIdx.y;
  const int b = bh >> 4, h = bh & 15;
  const u16* Qp = Qg + (size_t)bh * T_SEQ * DHEAD;
  const u16* Kp = Kg + (size_t)bh * T_SEQ * DHEAD;
  const u16* Vp = Vtg + (size_t)bh * DHEAD * T_SEQ;

  auto stage_kv = [&](u16* Ksd, u16* Vtd, int kvb) {
#pragma unroll
    for (int i = 0; i < 2; i++) {
      int c = i * 256 + tid;
      int r = c >> 3;
      int sw = ((c & 7) ^ (r & 7)) << 3;  // pre-swizzled global col slot
      gld16(&Kp[(size_t)(kvb + r) * DHEAD + sw], &Ksd[c * 8]);
      gld16(&Vp[(size_t)r * T_SEQ + kvb + sw], &Vtd[c * 8]);
    }
  };

#pragma unroll
  for (int p = 0; p < 2; p++) {
    const int qt = p ? (31 - j) : j;
    const int qb = qt * 64;

    __syncthreads();  // prior phase's Ps / KV-buffer readers done
#pragma unroll
    for (int i = 0; i < 2; i++) {  // stage Q (64x64, padded 72)
      int c = i * 256 + tid;
      int r = c >> 3, kk = (c & 7) << 3;
      *(uint4v*)&Qs[r * 72 + kk] =
          *(const uint4v*)&Qp[(size_t)(qb + r) * DHEAD + kk];
    }
    stage_kv(smem + 4608, smem + 12800, 0);  // KV tile 0 -> buf 0
    __syncthreads();                         // drains lgkm (Q) + vmcnt (KV DMA)

    short8 qf[2];
#pragma unroll
    for (int ks = 0; ks < 2; ks++)
      qf[ks] = *(const short8*)&Qs[q_local * 72 + ks * 32 + lk];

    float mst = NEG_BIG, lst = 0.f;
    f32x4 oacc[4];
#pragma unroll
    for (int nd = 0; nd < 4; nd++) oacc[nd] = (f32x4)0.0f;

    const int ntiles = qt + 1;
    int cur = 0;
    for (int kt = 0; kt < ntiles; kt++) {
      u16* Ksc = smem + 4608 + cur * 4096;
      u16* Vtc = smem + 12800 + cur * 4096;
      if (kt + 1 < ntiles)  // prefetch next KV tile into the other buffer
        stage_kv(smem + 4608 + (cur ^ 1) * 4096,
                 smem + 12800 + (cur ^ 1) * 4096, (kt + 1) * 64);

      // S^T: s[kvt] has col=lane&15=q_local, row(quad*4+r)=kv within tile
      f32x4 s[4];
      __builtin_amdgcn_s_setprio(1);
#pragma unroll
      for (int kvt = 0; kvt < 4; kvt++) {
        f32x4 a = (f32x4)0.0f;
#pragma unroll
        for (int ks = 0; ks < 2; ks++) {
          short8 kf = *(const short8*)&Ksc[(kvt * 16 + lrow) * 64 +
                                           ((((ks << 2) + quad) ^ rsw) << 3)];
          a = MFMA_BF16(kf, qf[ks], a);
        }
        s[kvt] = a;
      }
      __builtin_amdgcn_s_setprio(0);

      if (kt == qt) {  // causal mask: only the diagonal tile needs it
#pragma unroll
        for (int kvt = 0; kvt < 4; kvt++)
#pragma unroll
          for (int r = 0; r < 4; r++)
            if (kvt * 16 + quad * 4 + r > q_local) s[kvt][r] = NEG_BIG;
      }

      // online softmax, per-lane scalar stats (one q-row per lane)
      float mx = s[0][0];
#pragma unroll
      for (int kvt = 0; kvt < 4; kvt++)
#pragma unroll
        for (int r = 0; r < 4; r++) mx = fmaxf(mx, s[kvt][r]);
      mx = fmaxf(mx, __shfl_xor(mx, 16));
      mx = fmaxf(mx, __shfl_xor(mx, 32));
      // T13 defer-max: skip O-rescale while max growth <= THR (P <= 2^8)
      if (!__all(mx <= mst + RESCALE_THR)) {
        float mn = fmaxf(mst, mx);
        float corr = EXP2(mst - mn);
        mst = mn;
        lst *= corr;
#pragma unroll
        for (int nd = 0; nd < 4; nd++) oacc[nd] *= corr;
      }
      float ls = 0.f;
#pragma unroll
      for (int kvt = 0; kvt < 4; kvt++)
#pragma unroll
        for (int r = 0; r < 4; r++) {
          float pv = EXP2(s[kvt][r] - mst);
          s[kvt][r] = pv;
          ls += pv;
        }
      ls += __shfl_xor(ls, 16);
      ls += __shfl_xor(ls, 32);
      lst += ls;

      // P store: row q_local, 4 consecutive kv per kvt -> packed b64 writes.
      // Truncation (rel err < 0.4%) saves ~48 VALU/iter. Wave-private rows:
      // no barrier needed between write and pf read.
#pragma unroll
      for (int kvt = 0; kvt < 4; kvt++) {
        uint2v pk;
        pk[0] = (__float_as_uint(s[kvt][0]) >> 16) |
                (__float_as_uint(s[kvt][1]) & 0xffff0000u);
        pk[1] = (__float_as_uint(s[kvt][2]) >> 16) |
                (__float_as_uint(s[kvt][3]) & 0xffff0000u);
        *(uint2v*)&Ps[q_local * 72 + kvt * 16 + quad * 4] = pk;
      }

      // O^T += V^T P^T: mfma(vf, pf) -> col=q_local, row=d within tile
      __builtin_amdgcn_s_setprio(1);
#pragma unroll
      for (int ks = 0; ks < 2; ks++) {
        short8 pf = *(const short8*)&Ps[q_local * 72 + ks * 32 + lk];
#pragma unroll
        for (int nd = 0; nd < 4; nd++) {
          short8 vf = *(const short8*)&Vtc[(nd * 16 + lrow) * 64 +
                                           ((((ks << 2) + quad) ^ rsw) << 3)];
          oacc[nd] = MFMA_BF16(vf, pf, oacc[nd]);
        }
      }
      __builtin_amdgcn_s_setprio(0);

      __syncthreads();  // next-tile DMA drained; this tile's readers done
      cur ^= 1;
    }

    // epilogue: lane owns q-row qb+q_local fully; d = nd*16 + quad*4 + r
    float inv = 1.f / lst;
    size_t rowbase = ((size_t)(b * T_SEQ + qb + q_local)) * DMODEL + h * DHEAD;
#pragma unroll
    for (int nd = 0; nd < 4; nd++) {
      uint2v pk;
      pk[0] = (unsigned)f2bf(oacc[nd][0] * inv) |
              ((unsigned)f2bf(oacc[nd][1] * inv) << 16);
      pk[1] = (unsigned)f2bf(oacc[nd][2] * inv) |
              ((unsigned)f2bf(oacc[nd][3] * inv) << 16);
      *(uint2v*)&Ob[rowbase + nd * 16 + quad * 4] = pk;
    }
  }
}

// ---------------------------------------------------------------- out proj (bf16)
__global__ __launch_bounds__(256) void gemm_out_bf(const u16* __restrict__ O,
                                                   const u16* __restrict__ Wo,
                                                   float* __restrict__ Out) {
  __shared__ __attribute__((aligned(16))) u16 As[2][128 * 32];
  __shared__ __attribute__((aligned(16))) u16 Bs[2][128 * 32];
  const int tid = threadIdx.x, lane = tid & 63, w = tid >> 6;
  const int wm = (w >> 1) * 64, wn = (w & 1) * 64;
  const int lrow = lane & 15;
  const int lk = (lane >> 4) << 3;
  const int lq = (lane >> 4) << 2;
  const int mBase = blockIdx.x * 128, nBase = blockIdx.y * 128;

  f32x4 acc[4][4];
#pragma unroll
  for (int mi = 0; mi < 4; mi++)
#pragma unroll
    for (int ni = 0; ni < 4; ni++) acc[mi][ni] = (f32x4)0.0f;

  auto stage = [&](int buf, int k0) {
#pragma unroll
    for (int i = 0; i < 2; i++) {
      int c = i * 256 + tid;
      int r = c >> 2, kk = (c & 3) << 3;
      gld16(&O[(size_t)(mBase + r) * 1024 + k0 + kk], &As[buf][c * 8]);
      gld16(&Wo[(size_t)(nBase + r) * 1024 + k0 + kk], &Bs[buf][c * 8]);
    }
  };

  stage(0, 0);
  __syncthreads();
  int cur = 0;
  for (int k0 = 0; k0 < 1024; k0 += 32) {
    if (k0 + 32 < 1024) stage(cur ^ 1, k0 + 32);
    short8 af[4], bf[4];
#pragma unroll
    for (int mi = 0; mi < 4; mi++)
      af[mi] = *(const short8*)&As[cur][(wm + mi * 16 + lrow) * 32 + lk];
#pragma unroll
    for (int ni = 0; ni < 4; ni++)
      bf[ni] = *(const short8*)&Bs[cur][(wn + ni * 16 + lrow) * 32 + lk];
#pragma unroll
    for (int mi = 0; mi < 4; mi++)
#pragma unroll
      for (int ni = 0; ni < 4; ni++)
        acc[mi][ni] = MFMA_BF16(af[mi], bf[ni], acc[mi][ni]);
    __syncthreads();
    cur ^= 1;
  }
#pragma unroll
  for (int mi = 0; mi < 4; mi++)
#pragma unroll
    for (int r = 0; r < 4; r++) {
      int m = mBase + wm + mi * 16 + lq + r;
#pragma unroll
      for (int ni = 0; ni < 4; ni++)
        Out[(size_t)m * DMODEL + nBase + wn + ni * 16 + lrow] = acc[mi][ni][r];
    }
}

// ---------------------------------------------------------------- launch
extern "C" void kernel_launch(void* const* d_in, const int* in_sizes, int n_in,
                              void* d_out, int out_size, void* d_ws,
                              size_t ws_size, hipStream_t stream) {
  const float* x = (const float*)d_in[0];
  const float* Wq = (const float*)d_in[1];
  const float* Wk = (const float*)d_in[2];
  const float* Wv = (const float*)d_in[3];
  const float* Wo = (const float*)d_in[4];
  float* out = (float*)d_out;

  u16* xh = (u16*)d_ws;      // 4M elems
  u16* wqh = xh + 4194304;   // 1M each
  u16* wkh = wqh + 1048576;
  u16* wvh = wkh + 1048576;
  u16* woh = wvh + 1048576;
  u16* Q = woh + 1048576;    // 4M each; V stored transposed (b,h,d,t)
  u16* K = Q + 4194304;
  u16* V = K + 4194304;
  u16* O = V + 4194304;      // total 48 MB

  cvt_all<<<dim3(4096), 256, 0, stream>>>(x, Wq, Wk, Wv, Wo, xh, wqh, wkh, wvh, woh);
  gemm_qkv<<<dim3(32, 8, 3), 256, 0, stream>>>(xh, wqh, wkh, wvh, Q, K, V);
  attn_snake<<<dim3(16, 32), 256, 0, stream>>>(Q, K, V, O);
  gemm_out_bf<<<dim3(32, 8), 256, 0, stream>>>(O, woh, out);
}